// Round 3
// baseline (3073.929 us; speedup 1.0000x reference)
//
#include <hip/hip_runtime.h>
#include <math.h>

#define B_ 32
#define C_ 256
#define T_ 4096
#define L_ 1024

// Sentinel convention: internal trellis state uses +/-1e30 instead of +/-inf.
// Emission addends are O(1e1..1e5) << ulp(1e30)=7.5e22, so 1e30+e == 1e30
// exactly: every stored float and every (chg>stay) bit is bit-identical to
// the previous +/-inf-internal version (which passed), and no clamping is
// needed at store time.

// ws layout:
//   lse     : B_*T_ floats                      (524288 B)
//   tstart  : B_ ints (padded to 128 B)         (offset 524288)
//   db      : B_*L_*64 uint64 decision bits     (offset 524416, 16 MB)
//             db[b][j-1][w], bit (t-1)&63 of word (t-1)>>6 = take at (t, j)
//   jout    : B_*T_ ushort packed path          (offset 17301632, 256 KB)
//             jout[b][k] = entry j | (active << 15)
#define DB_OFF   ((size_t)524416)
#define JOUT_OFF ((size_t)17301632)
#define WS_NEED  ((size_t)17563776)

// ---------------------------------------------------------------------------
// Kernel 1: lse[b, t] = logsumexp over classes of logits[b, :, t]
// ---------------------------------------------------------------------------
__global__ __launch_bounds__(256) void lse_kernel(const float* __restrict__ logits,
                                                  float* __restrict__ lse) {
  const int b  = blockIdx.x >> 8;          // 256 t-chunks per batch
  const int t0 = (blockIdx.x & 255) << 4;  // 16 t per chunk
  const int c  = threadIdx.x;
  const float* p = logits + (((size_t)b << 8) + (size_t)c) * T_ + t0;
  float4 v0 = *(const float4*)(p + 0);
  float4 v1 = *(const float4*)(p + 4);
  float4 v2 = *(const float4*)(p + 8);
  float4 v3 = *(const float4*)(p + 12);

  __shared__ float lds[16][257];
  lds[ 0][c] = v0.x; lds[ 1][c] = v0.y; lds[ 2][c] = v0.z; lds[ 3][c] = v0.w;
  lds[ 4][c] = v1.x; lds[ 5][c] = v1.y; lds[ 6][c] = v1.z; lds[ 7][c] = v1.w;
  lds[ 8][c] = v2.x; lds[ 9][c] = v2.y; lds[10][c] = v2.z; lds[11][c] = v2.w;
  lds[12][c] = v3.x; lds[13][c] = v3.y; lds[14][c] = v3.z; lds[15][c] = v3.w;
  __syncthreads();

  const int w = threadIdx.x >> 6, lane = threadIdx.x & 63;
  for (int s = w; s < 16; s += 4) {
    float x0 = lds[s][lane], x1 = lds[s][lane + 64];
    float x2 = lds[s][lane + 128], x3 = lds[s][lane + 192];
    float m = fmaxf(fmaxf(x0, x1), fmaxf(x2, x3));
#pragma unroll
    for (int d = 32; d; d >>= 1) m = fmaxf(m, __shfl_xor(m, d, 64));
    float sum = expf(x0 - m) + expf(x1 - m) + expf(x2 - m) + expf(x3 - m);
#pragma unroll
    for (int d = 32; d; d >>= 1) sum += __shfl_xor(sum, d, 64);
    if (lane == 0) lse[b * T_ + t0 + s] = m + logf(sum);
  }
}

// ---------------------------------------------------------------------------
// Kernel 2: trellis. ONE WAVE per batch (64 threads); lane owns 17 register
// cells j = 16*lane + k (k=0..16; cell16 duplicates next lane's cell0 except
// on lane 63 where it is the real j=1024). No LDS, no barriers; the only
// cross-lane op is one shfl_up per step whose result has 16 steps of slack
// before it reaches the lane's last cell. Emissions gathered per 4-step chunk
// directly from global (L1-resident working set: 256 rows x 64B). Take bits
// accumulate MSB-first per 32 steps, bitreversed and stored as db u64 words
// per 64 steps (cells k=1..16 -> rows 16*lane .. 16*lane+15: exact partition).
// ---------------------------------------------------------------------------
__global__ __launch_bounds__(64) void trellis_kernel(const float* __restrict__ logits,
                                                     const int* __restrict__ tokens,
                                                     const float* __restrict__ lseg,
                                                     float* __restrict__ out,
                                                     unsigned long long* __restrict__ db) {
  const int b = blockIdx.x;
  const int lane = threadIdx.x;
  const int j0 = lane << 4;
  const bool lane0 = (lane == 0);

  const float* lgb = logits + (size_t)b * C_ * T_;  // [c][t]
  const float* lg0 = lgb;                           // class 0 row
  const float* lsp = lseg + b * T_;
  float* tre = out + (size_t)b * (T_ + 1) * (L_ + 1);
  const bool wdb = (db != nullptr);
  unsigned long long* dbl = db + (size_t)b * L_ * 64;

  // token gather offsets: cell k uses tokens[j0+k-1] (k=0 on lane 0: dummy)
  int off[17];
#pragma unroll
  for (int kk = 0; kk < 17; ++kk) {
    int idx = j0 + kk - 1;
    idx = idx < 0 ? 0 : idx;
    off[kk] = tokens[b * L_ + idx] * T_;
  }

  // state
  float v[17];
#pragma unroll
  for (int kk = 0; kk < 17; ++kk) v[kk] = -1e30f;
  if (lane0) v[0] = 0.f;
  float cum = 0.f;  // uniform col0 cumsum

  // row 0 store
  {
    float4 o;
    o.x = v[0]; o.y = v[1]; o.z = v[2]; o.w = v[3];
    *(float4*)(tre + j0 + 0) = o;
    o.x = v[4]; o.y = v[5]; o.z = v[6]; o.w = v[7];
    *(float4*)(tre + j0 + 4) = o;
    o.x = v[8]; o.y = v[9]; o.z = v[10]; o.w = v[11];
    *(float4*)(tre + j0 + 8) = o;
    o.x = v[12]; o.y = v[13]; o.z = v[14]; o.w = v[15];
    *(float4*)(tre + j0 + 12) = o;
    if (lane == 63) tre[L_] = v[16];
  }

  float* rowp = tre + (L_ + 1);  // row t+1, starting at t=0
  unsigned acc[16];
#pragma unroll
  for (int kk = 0; kk < 16; ++kk) acc[kk] = 0u;

  // 32 steps: 8 chunks of 4 (chunk loop deliberately NOT unrolled: icache)
  auto run32 = [&](int tbase) {
#pragma unroll 1
    for (int c8 = 0; c8 < 8; ++c8) {
      const int t0 = tbase + (c8 << 2);
      float4 gk[17];
#pragma unroll
      for (int kk = 0; kk < 17; ++kk)
        gk[kk] = *(const float4*)(lgb + (off[kk] + t0));
      const float4 lsw = *(const float4*)(lsp + t0);
      const float4 zw = *(const float4*)(lg0 + t0);
#pragma unroll
      for (int s = 0; s < 4; ++s) {
        const int t = t0 + s;
        const float lss = ((const float*)&lsw)[s];
        const float em0 = ((const float*)&zw)[s] - lss;   // emission[t][0]
        const float bnd = __shfl_up(v[15], 1, 64);        // prev lane cell15 (old)
#pragma unroll
        for (int kk = 16; kk >= 1; --kk) {                // descending: in-place safe
          const float em = ((const float*)&gk[kk])[s] - lss;
          const float stay = v[kk] + em0;
          const float chg = v[kk - 1] + em;
          v[kk] = fmaxf(stay, chg);
          acc[kk - 1] = (acc[kk - 1] << 1) | (unsigned)(chg > stay);
        }
        {
          const float em = ((const float*)&gk[0])[s] - lss;
          const float stay = v[0] + em0;
          const float chg = bnd + em;
          const float nv0 = fmaxf(stay, chg);
          cum += em0;
          const float c0n = (t + 1 >= T_ + 1 - L_) ? 1e30f : cum;
          v[0] = lane0 ? c0n : nv0;
        }
        float4 o;
        o.x = v[0]; o.y = v[1]; o.z = v[2]; o.w = v[3];
        *(float4*)(rowp + j0 + 0) = o;
        o.x = v[4]; o.y = v[5]; o.z = v[6]; o.w = v[7];
        *(float4*)(rowp + j0 + 4) = o;
        o.x = v[8]; o.y = v[9]; o.z = v[10]; o.w = v[11];
        *(float4*)(rowp + j0 + 8) = o;
        o.x = v[12]; o.y = v[13]; o.z = v[14]; o.w = v[15];
        *(float4*)(rowp + j0 + 12) = o;
        if (lane == 63) rowp[L_] = v[16];
        rowp += (L_ + 1);
      }
    }
  };

#pragma unroll 1
  for (int win = 0; win < 64; ++win) {
    run32(win * 64);
    unsigned wlo[16];
#pragma unroll
    for (int kk = 0; kk < 16; ++kk) {
      wlo[kk] = __builtin_bitreverse32(acc[kk]);
      acc[kk] = 0u;
    }
    run32(win * 64 + 32);
    if (wdb) {
#pragma unroll
      for (int kk = 0; kk < 16; ++kk) {
        const unsigned long long wd =
            (unsigned long long)wlo[kk] |
            ((unsigned long long)__builtin_bitreverse32(acc[kk]) << 32);
        dbl[(size_t)(j0 + kk) * 64 + win] = wd;
        acc[kk] = 0u;
      }
    } else {
#pragma unroll
      for (int kk = 0; kk < 16; ++kk) acc[kk] = 0u;
    }
  }
}

// ---------------------------------------------------------------------------
// Kernel 3: t_start[b] = argmax_t trellis[b, t, L]  (first max, like jnp.argmax)
// ---------------------------------------------------------------------------
__global__ __launch_bounds__(256) void argmax_kernel(const float* __restrict__ out,
                                                     int* __restrict__ tstart) {
  const int b = blockIdx.x;
  const float* tre = out + (size_t)b * (T_ + 1) * (L_ + 1);
  float bv = -INFINITY;
  int bi = 0x7fffffff;
  for (int t = threadIdx.x; t <= T_; t += 256) {
    float v = tre[(size_t)t * (L_ + 1) + L_];
    if (v > bv || (v == bv && t < bi)) { bv = v; bi = t; }
  }
  __shared__ float sv[256];
  __shared__ int si[256];
  sv[threadIdx.x] = bv; si[threadIdx.x] = bi;
  __syncthreads();
  for (int d = 128; d; d >>= 1) {
    if (threadIdx.x < d) {
      float ov = sv[threadIdx.x + d]; int oi = si[threadIdx.x + d];
      if (ov > sv[threadIdx.x] || (ov == sv[threadIdx.x] && oi < si[threadIdx.x])) {
        sv[threadIdx.x] = ov; si[threadIdx.x] = oi;
      }
    }
    __syncthreads();
  }
  if (threadIdx.x == 0) tstart[b] = si[0];
}

// ---------------------------------------------------------------------------
// Kernel 4a: path chase, WAVE-PARALLEL. One wave per batch. Rows are visited
// in strictly decreasing j order -> row addresses are deterministic: a 4-deep
// register ring prefetches rows ahead (hides L2/HBM latency). Per level: one
// coalesced 512B row load (64 lanes x u64), ballot+clz find the highest take
// bit <= t-1 in O(1); jo run-fills are lane-striped coalesced stores.
// Semantics identical to the (passing) serial word-scan version.
// ---------------------------------------------------------------------------
__global__ __launch_bounds__(64) void backtrack_path_kernel(
    const unsigned long long* __restrict__ db,
    const int* __restrict__ tstart,
    unsigned short* __restrict__ jout) {
  const int b = blockIdx.x;
  const int lane = threadIdx.x;
  const int ts = tstart[b];
  unsigned short* jo = jout + (size_t)b * T_;
  const unsigned long long* dbb = db + (size_t)b * L_ * 64;

  auto fill = [&](int k0, int k1, int val) {
    for (int kk = k0 + lane; kk <= k1; kk += 64) jo[kk] = (unsigned short)val;
  };

  if (ts < 1) {          // never active; j frozen at L_
    fill(0, T_ - 1, L_);
    return;
  }

  int j = L_;
  int t = ts;
  // ring prefetch: r_d = row(j-1-d), rows clamped at 0 (harmless dup loads)
  auto rowload = [&](int r) {
    r = r < 0 ? 0 : r;
    return dbb[(size_t)r * 64 + lane];
  };
  unsigned long long r0 = rowload(j - 1), r1 = rowload(j - 2),
                     r2 = rowload(j - 3), r3 = rowload(j - 4);

  while (true) {
    // highest set bit at position <= t-1 in row (j-1)
    const int p = t - 1;
    const int wcur = p >> 6;
    unsigned long long w = r0;
    if (lane > wcur) w = 0ull;
    else if (lane == wcur) w &= (~0ull >> (63 - (p & 63)));
    const unsigned long long nz = __ballot(w != 0ull);
    if (nz == 0ull) {
      // no take down to t=1: active stays through t=1, then done
      fill(ts - t, ts - 1, j | 0x8000);
      fill(ts, T_ - 1, j);
      return;
    }
    const int hl = 63 - __clzll(nz);
    const unsigned long long wh = __shfl(w, hl, 64);
    const int tTake = (hl << 6) + (63 - __clzll(wh)) + 1;
    const int kTake = ts - tTake;
    fill(ts - t, kTake, j | 0x8000);   // stays then take, entry j, active
    j -= 1;
    if (j == 0 || tTake <= 1) {        // done after the take
      fill(kTake + 1, T_ - 1, j);
      return;
    }
    t = tTake - 1;
    r0 = r1; r1 = r2; r2 = r3;
    r3 = rowload(j - 4);
  }
}

// ---------------------------------------------------------------------------
// Kernel 4b: fully parallel emit. One thread per (b, k). Recomputes the take
// decision from the sentinel trellis with the exact formula of the (passing)
// serial backtrack; the j trajectory comes from jout.
// ---------------------------------------------------------------------------
__global__ __launch_bounds__(256) void backtrack_emit_kernel(
    const float* __restrict__ logits, const int* __restrict__ tokens,
    const float* __restrict__ lseg, const int* __restrict__ tstart,
    const unsigned short* __restrict__ jout, float* __restrict__ out) {
  const int idx = blockIdx.x * 256 + threadIdx.x;
  const int b = idx >> 12;                     // T_ = 4096
  const int k = idx & (T_ - 1);
  const float* tre = out + (size_t)b * (T_ + 1) * (L_ + 1);
  const float* lg = logits + (size_t)b * C_ * T_;
  const int ts = tstart[b];
  const unsigned short pk = jout[(size_t)b * T_ + k];
  const int j = pk & 0x7fff;
  const bool active = (pk & 0x8000) != 0;
  const int t = ts - k;
  const int tm1 = (t - 1 > 0) ? t - 1 : 0;
  const int jm1 = (j - 1 > 0) ? j - 1 : 0;
  const float ls = lseg[b * T_ + tm1];
  const float e0 = lg[tm1] - ls;               // emission[tm1][0]
  const int tk = tokens[b * L_ + jm1];
  const float ec = lg[(size_t)tk * T_ + tm1] - ls;
  const float stayed = tre[(size_t)tm1 * (L_ + 1) + j] + e0;
  const float changed = tre[(size_t)tm1 * (L_ + 1) + jm1] + ec;
  const bool take = changed > stayed;
  const size_t OBASE = (size_t)B_ * (T_ + 1) * (L_ + 1);
  float* pj = out + OBASE + (size_t)b * T_;
  float* pt = pj + (size_t)B_ * T_;
  float* pp = pt + (size_t)B_ * T_;
  float* pv = pp + (size_t)B_ * T_;
  pj[k] = (float)jm1;
  pt[k] = (float)tm1;
  pp[k] = expf(take ? ec : e0);
  pv[k] = active ? 1.f : 0.f;
}

// ---------------------------------------------------------------------------
// Kernel 4 (fallback): serial backtrack, used only if ws_size is too small
// for the decision-bit workspace.
// ---------------------------------------------------------------------------
__global__ __launch_bounds__(64) void backtrack_kernel(const float* __restrict__ logits,
                                                       const int* __restrict__ tokens,
                                                       const float* __restrict__ lseg,
                                                       const int* __restrict__ tstart,
                                                       float* __restrict__ out) {
  const int b = blockIdx.x;
  if (threadIdx.x != 0) return;
  const float* tre = out + (size_t)b * (T_ + 1) * (L_ + 1);
  const float* lg = logits + (size_t)b * C_ * T_;
  const float* lsep = lseg + b * T_;
  const int* tkp = tokens + b * L_;
  const size_t OBASE = (size_t)B_ * (T_ + 1) * (L_ + 1);
  float* pj = out + OBASE + (size_t)b * T_;
  float* pt = pj + (size_t)B_ * T_;
  float* pp = pt + (size_t)B_ * T_;
  float* pv = pp + (size_t)B_ * T_;

  const int ts = tstart[b];
  int j = L_;
  bool done = false;
  for (int k = 0; k < T_; ++k) {
    const int t = ts - k;
    const bool active = (t >= 1) && !done;
    const int tm1 = (t - 1 > 0) ? t - 1 : 0;
    const int jm1 = (j - 1 > 0) ? j - 1 : 0;
    const float ls = lsep[tm1];
    const float e0 = lg[tm1] - ls;
    const int tk = tkp[jm1];
    const float ec = lg[(size_t)tk * T_ + tm1] - ls;
    const float stayed = tre[(size_t)tm1 * (L_ + 1) + j] + e0;
    const float changed = tre[(size_t)tm1 * (L_ + 1) + jm1] + ec;
    const bool take = changed > stayed;
    pj[k] = (float)jm1;
    pt[k] = (float)tm1;
    pp[k] = expf(take ? ec : e0);
    pv[k] = active ? 1.f : 0.f;
    if (active && take) j -= 1;
    done = done || (j == 0) || (t <= 1);
  }
}

// ---------------------------------------------------------------------------
extern "C" void kernel_launch(void* const* d_in, const int* in_sizes, int n_in,
                              void* d_out, int out_size, void* d_ws, size_t ws_size,
                              hipStream_t stream) {
  const float* logits = (const float*)d_in[0];
  const int* tokens = (const int*)d_in[1];
  float* out = (float*)d_out;
  float* lse = (float*)d_ws;
  int* tstart = (int*)(lse + (size_t)B_ * T_);

  const bool fast = (ws_size >= WS_NEED);
  unsigned long long* db =
      fast ? (unsigned long long*)((char*)d_ws + DB_OFF) : nullptr;
  unsigned short* jout =
      fast ? (unsigned short*)((char*)d_ws + JOUT_OFF) : nullptr;

  lse_kernel<<<B_ * (T_ / 16), 256, 0, stream>>>(logits, lse);
  trellis_kernel<<<B_, 64, 0, stream>>>(logits, tokens, lse, out, db);
  argmax_kernel<<<B_, 256, 0, stream>>>(out, tstart);
  if (fast) {
    backtrack_path_kernel<<<B_, 64, 0, stream>>>(db, tstart, jout);
    backtrack_emit_kernel<<<B_ * (T_ / 256), 256, 0, stream>>>(
        logits, tokens, lse, tstart, jout, out);
  } else {
    backtrack_kernel<<<B_, 64, 0, stream>>>(logits, tokens, lse, tstart, out);
  }
}